// Round 9
// baseline (749.195 us; speedup 1.0000x reference)
//
#include <hip/hip_runtime.h>
#include <cstdint>
#include <cstddef>

#define UNITS 25
#define IN_DIM 64
#define BATCH 256
#define SEQ 2048
#define BT (BATCH * SEQ)
#define L2E 1.442695040888963f

typedef _Float16 h2t __attribute__((ext_vector_type(2)));

#define R13(M) M(0) M(1) M(2) M(3) M(4) M(5) M(6) M(7) M(8) M(9) M(10) M(11) M(12)

// f32 pair -> packed f16 (v_cvt_pkrtz_f16_f32)
__device__ __forceinline__ unsigned pk16(float lo, float hi) {
    return __builtin_bit_cast(unsigned, __builtin_amdgcn_cvt_pkrtz(lo, hi));
}
__device__ __forceinline__ float lo16(unsigned u) {
    return (float)__builtin_bit_cast(h2t, u).x;
}
__device__ __forceinline__ float hi16(unsigned u) {
    return (float)__builtin_bit_cast(h2t, u).y;
}
// 2-way f16 dot with f32 accumulate (v_dot2_f32_f16)
__device__ __forceinline__ float fdot2_(unsigned w, unsigned h, float c) {
#if __has_builtin(__builtin_amdgcn_fdot2)
    return __builtin_amdgcn_fdot2(__builtin_bit_cast(h2t, w),
                                  __builtin_bit_cast(h2t, h), c, false);
#else
    h2t W = __builtin_bit_cast(h2t, w), H = __builtin_bit_cast(h2t, h);
    return fmaf((float)W.x, (float)H.x, fmaf((float)W.y, (float)H.y, c));
#endif
}
// swap within lane pairs (0<->1,...): quad_perm(1,0,3,2)
__device__ __forceinline__ float dswap(float v) {
    return __int_as_float(__builtin_amdgcn_mov_dpp(__float_as_int(v), 0xB1, 0xF, 0xF, true));
}
// lane 4q+p gets lane 4q+2's value: quad_perm(2,2,2,2)
__device__ __forceinline__ float dpp2(float v) {
    return __int_as_float(__builtin_amdgcn_mov_dpp(__float_as_int(v), 0xAA, 0xF, 0xF, true));
}
__device__ __forceinline__ unsigned rdlu(unsigned v, int lane) {
    return (unsigned)__builtin_amdgcn_readlane((int)v, lane);
}
__device__ __forceinline__ float sig_raw(float a) {      // sigma from pre-scaled acc
    return __builtin_amdgcn_rcpf(1.0f + __builtin_amdgcn_exp2f(a));
}
__device__ __forceinline__ float tanh5(float c) {        // tanh(c), c unscaled
    return fmaf(2.0f, __builtin_amdgcn_rcpf(
        1.0f + __builtin_amdgcn_exp2f(-2.0f * L2E * c)), -1.0f);
}
// pinned global load: volatile asm result cannot be rematerialized by the
// compiler -> the value MUST stay resident in a VGPR.
__device__ __forceinline__ unsigned ldpin(const unsigned* p) {
    unsigned v;
    asm volatile("global_load_dword %0, %1, off\n\ts_waitcnt vmcnt(0)"
                 : "=v"(v) : "v"(p) : "memory");
    return v;
}
// producer/consumer barrier: drain LDS ops, then workgroup barrier. Raw asm
// so it is legal inside wave-uniform (but compiler-divergent) branches.
__device__ __forceinline__ void wgbar() {
    asm volatile("s_waitcnt lgkmcnt(0)\n\ts_barrier" ::: "memory");
}

// Column order (shared prep/proj/scan): c<50 = pass A (even=i, odd=f);
// c>=50 = pass B (even=c-gate[tanh], odd=o). unit u = ((c%50)>>1).
// Activation scale folded into weights/biases: tanh cols -2*L2E, else -L2E.

__device__ unsigned g_w1[13 * 100];    // layer-1 recurrent, f16 k-pairs, scaled
__device__ unsigned g_wx[13 * 100];    // layer-2 input (h1) weights
__device__ unsigned g_wh[13 * 100];    // layer-2 recurrent
__device__ unsigned g_wo[13];          // head weights, f16 pairs, unscaled
__device__ unsigned g_Wp16[100 * 32];  // proj weights: [c][kpair] f16 pairs, scaled
__device__ float    g_bp[100];         // proj bias [c], scaled

// ---------------------------------------------------------------------------
__global__ void prep_kernel(const float* __restrict__ l1_Whi, const float* __restrict__ l1_Whf,
                            const float* __restrict__ l1_Whc, const float* __restrict__ l1_Who,
                            const float* __restrict__ l1_Wxi, const float* __restrict__ l1_Wxf,
                            const float* __restrict__ l1_Wxc, const float* __restrict__ l1_Wxo,
                            const float* __restrict__ l1_bi,  const float* __restrict__ l1_bf,
                            const float* __restrict__ l1_bc,  const float* __restrict__ l1_bo,
                            const float* __restrict__ l2_Wxi, const float* __restrict__ l2_Wxf,
                            const float* __restrict__ l2_Wxc, const float* __restrict__ l2_Wxo,
                            const float* __restrict__ l2_Whi, const float* __restrict__ l2_Whf,
                            const float* __restrict__ l2_Whc, const float* __restrict__ l2_Who,
                            const float* __restrict__ Wout) {
    const int c = threadIdx.x;
    if (c < 100) {
        const int half = (c >= 50);
        const int l = half ? c - 50 : c;
        const int u = l >> 1;
        const int par = l & 1;
        const float s = (half && !par) ? (-2.0f * L2E) : (-L2E);
        const float* W1 = half ? (par ? l1_Who : l1_Whc) : (par ? l1_Whf : l1_Whi);
        const float* WX = half ? (par ? l2_Wxo : l2_Wxc) : (par ? l2_Wxf : l2_Wxi);
        const float* WH = half ? (par ? l2_Who : l2_Whc) : (par ? l2_Whf : l2_Whi);
        const float* WI = half ? (par ? l1_Wxo : l1_Wxc) : (par ? l1_Wxf : l1_Wxi);
        const float* bI = half ? (par ? l1_bo  : l1_bc)  : (par ? l1_bf  : l1_bi);
        for (int i = 0; i < 13; ++i) {
            const int k0 = 2 * i, k1 = 2 * i + 1;
            const float a1 = s * W1[k0 * UNITS + u];
            const float b1 = (k1 < UNITS) ? s * W1[k1 * UNITS + u] : 0.f;
            g_w1[i * 100 + c] = pk16(a1, b1);
            const float ax = s * WX[k0 * UNITS + u];
            const float bx = (k1 < UNITS) ? s * WX[k1 * UNITS + u] : 0.f;
            g_wx[i * 100 + c] = pk16(ax, bx);
            const float ah = s * WH[k0 * UNITS + u];
            const float bh = (k1 < UNITS) ? s * WH[k1 * UNITS + u] : 0.f;
            g_wh[i * 100 + c] = pk16(ah, bh);
        }
        for (int kp = 0; kp < 32; ++kp)
            g_Wp16[c * 32 + kp] = pk16(s * WI[(2 * kp) * UNITS + u],
                                       s * WI[(2 * kp + 1) * UNITS + u]);
        g_bp[c] = s * bI[u];
    }
    if (c == 100) {
        for (int i = 0; i < 13; ++i) {
            const int k1 = 2 * i + 1;
            g_wo[i] = pk16(Wout[2 * i], (k1 < UNITS) ? Wout[k1] : 0.f);
        }
    }
}

// ---------------------------------------------------------------------------
// proj: pre2h[row][c] = pk16(scaled pre of col c, col c+50).  2 rows/thread.
// R9: COALESCED x reads via LDS round-trip. Old pattern (per-thread row
// reads, 256B lane stride) = 64 txns per wave load instr (~8.4M read txns),
// the same pathology the R5 store fix removed on the write side (-120us).
// Now: 128-row groups loaded coalesced (consecutive lanes -> consecutive
// 16B), converted to f16 pairs in LDS (pad 36 dwords/row), owner threads
// pull their row into the same xp[2][8] regs. The staging buffer is reused
// as the output stage ob (pad 11 -> conflict-free writes); flush emits
// dwordx2 (all run starts even). Compute loop and f32 association are
// byte-identical to R5/R8.
// ---------------------------------------------------------------------------
#define PCH 10
#define OB1 2816
__global__ __launch_bounds__(256, 2)
void proj_kernel(const float* __restrict__ x, unsigned* __restrict__ pre2h) {
    __shared__ unsigned wls[100 * 32];
    __shared__ float bls[100];
    __shared__ unsigned sb[5632];       // stage (128*36=4608) / ob reuse (2*2816)
    const int tid = threadIdx.x;
    for (int i = tid; i < 3200; i += 256) wls[i] = g_Wp16[i];
    if (tid < 100) bls[tid] = g_bp[tid];

    // ---- staged, coalesced load of this block's 512 rows into xp regs ----
    uint4 xp[2][8];
    const bool lowhalf = (tid < 128);
    #pragma unroll
    for (int g = 0; g < 4; ++g) {
        __syncthreads();                 // prior stage's reads done
        const float4* xg = (const float4*)(x + ((size_t)blockIdx.x * 512 + g * 128) * IN_DIM);
        #pragma unroll
        for (int k = 0; k < 8; ++k) {
            const int q = tid + (k << 8);          // f4 index in 128-row group
            const float4 a = xg[q];
            const int row = q >> 4;                // 16 f4 per row
            const int col = (q << 1) & 31;         // 2 dwords per f4
            *(uint2*)&sb[row * 36 + col] = make_uint2(pk16(a.x, a.y), pk16(a.z, a.w));
        }
        __syncthreads();
        // owners: g0 -> tid<128 reads xp[0]; g1 -> tid>=128 xp[0];
        //         g2 -> tid<128 xp[1];      g3 -> tid>=128 xp[1]
        const bool mine = ((g & 1) == (lowhalf ? 0 : 1));
        if (mine) {
            const int inrow = lowhalf ? tid : tid - 128;
            const unsigned* rp = sb + inrow * 36;
            uint4* dst = xp[g >> 1];
            #pragma unroll
            for (int j = 0; j < 8; ++j) dst[j] = *(const uint4*)(rp + 4 * j);
        }
    }
    __syncthreads();                     // all xp reads done before ob reuse

    // ---- compute + staged coalesced flush (as R5/R8) ----
    #pragma unroll 1
    for (int ch = 0; ch < 50; ch += PCH) {
        #pragma unroll 1
        for (int cc = 0; cc < PCH; ++cc) {
            const int c = ch + cc;
            const uint4* wA = (const uint4*)(wls + c * 32);          // col c
            const uint4* wB = (const uint4*)(wls + (c + 50) * 32);   // col c+50
            float aA0 = bls[c],      aA1 = 0.f;
            float bA0 = 0.f, bA1 = 0.f;
            float aB0 = bls[c + 50], aB1 = 0.f, bB0 = 0.f, bB1 = 0.f;
            float cA0 = bls[c],      cA1 = 0.f, dA0 = 0.f, dA1 = 0.f; // row1
            float cB0 = bls[c + 50], cB1 = 0.f, dB0 = 0.f, dB1 = 0.f;
            #pragma unroll
            for (int j = 0; j < 8; ++j) {
                const uint4 wa = wA[j], wb = wB[j];
                const uint4 x0 = xp[0][j], x1 = xp[1][j];
                aA0 = fdot2_(wa.x, x0.x, aA0); bA0 = fdot2_(wa.y, x0.y, bA0);
                aA1 = fdot2_(wa.z, x0.z, aA1); bA1 = fdot2_(wa.w, x0.w, bA1);
                aB0 = fdot2_(wb.x, x0.x, aB0); bB0 = fdot2_(wb.y, x0.y, bB0);
                aB1 = fdot2_(wb.z, x0.z, aB1); bB1 = fdot2_(wb.w, x0.w, bB1);
                cA0 = fdot2_(wa.x, x1.x, cA0); dA0 = fdot2_(wa.y, x1.y, dA0);
                cA1 = fdot2_(wa.z, x1.z, cA1); dA1 = fdot2_(wa.w, x1.w, dA1);
                cB0 = fdot2_(wb.x, x1.x, cB0); dB0 = fdot2_(wb.y, x1.y, dB0);
                cB1 = fdot2_(wb.z, x1.z, cB1); dB1 = fdot2_(wb.w, x1.w, dB1);
            }
            sb[tid * 11 + cc]       = pk16((aA0 + aA1) + (bA0 + bA1),
                                           (aB0 + aB1) + (bB0 + bB1));
            sb[OB1 + tid * 11 + cc] = pk16((cA0 + cA1) + (dA0 + dA1),
                                           (cB0 + cB1) + (dB0 + dB1));
        }
        __syncthreads();
        #pragma unroll
        for (int g2 = 0; g2 < 2; ++g2) {
            const size_t rowbase = ((size_t)blockIdx.x * 512 + g2 * 256) * 50 + ch;
            const unsigned* obp = sb + g2 * OB1;
            #pragma unroll
            for (int k = 0; k < 5; ++k) {
                const int p = tid + (k << 8);       // pair index 0..1279
                const int row = p / 5;
                const int m2 = (p - row * 5) << 1;  // 0,2,4,6,8
                const unsigned u0 = obp[row * 11 + m2];
                const unsigned u1 = obp[row * 11 + m2 + 1];
                *(uint2*)(pre2h + rowbase + (size_t)row * 50 + m2) = make_uint2(u0, u1);
            }
        }
        __syncthreads();
    }
}

// ---------------------------------------------------------------------------
// scan: 1 batch element per block, TWO waves on two SIMDs, pipelined
// (R1 structure, proven 431-444us; R2/R4 restructures both regressed):
//   wave0 = layer-1 (act + w1 dots + wx dots)  -> xA,xB into LDS slot
//   wave1 = layer-2 (wh dots + act + h2 store), one group (4 steps) behind.
// ---------------------------------------------------------------------------
template<bool HOFF>
__global__ __attribute__((amdgpu_waves_per_eu(1, 1))) __launch_bounds__(128)
void lstm_scan_kernel(const unsigned* __restrict__ pre2h,
                      const float* __restrict__ l2_bi, const float* __restrict__ l2_bf,
                      const float* __restrict__ l2_bc, const float* __restrict__ l2_bo,
                      const float* __restrict__ bout,
                      float* __restrict__ h2buf, float* __restrict__ out) {
    __shared__ float2 xsl[2][4][64];                 // [slot][sub-step][lane]
    const int tid = threadIdx.x;
    const int l   = tid & 63;
    const int b   = blockIdx.x;
    const int lc  = (l < 50) ? l : 49;   // lanes 50..63 compute junk, never read
    const int uu  = lc >> 1;
    const bool odd = (l & 1);
    // pass-B activation per parity: even lane -> tanh form, odd -> sigmoid
    const float tA = odd ? 1.0f : 2.0f;
    const float tC = odd ? 0.0f : -1.0f;

    if (tid < 64) {
        // ================= wave 0: layer 1 + layer-2 input dots ===========
        const float b2A = (odd ? l2_bf[uu] : l2_bi[uu]) * (-L2E);
        const float b2B = odd ? (l2_bo[uu] * (-L2E)) : (l2_bc[uu] * (-2.0f * L2E));
        #define LW(i) const unsigned w1A_##i = ldpin(g_w1 + (i)*100 + lc);      \
                      const unsigned w1B_##i = ldpin(g_w1 + (i)*100 + 50 + lc); \
                      const unsigned wxA_##i = ldpin(g_wx + (i)*100 + lc);      \
                      const unsigned wxB_##i = ldpin(g_wx + (i)*100 + 50 + lc);
        R13(LW)
        #undef LW
        #define DH(i) unsigned s1_##i = 0u;
        R13(DH)
        #undef DH
        float c1 = 0.f;

        const unsigned* prow = pre2h + (size_t)b * SEQ * 50 + lc;
        // carried F1 accumulators, primed from pre(0) (h1(-1)=0)
        const unsigned p0 = prow[0];
        float aA = lo16(p0), aB = hi16(p0);
        unsigned q1 = prow[50], q2 = prow[100], q3 = prow[150];

        auto stepA = [&](unsigned pw, float2* xs) {
            // ---- layer-1 activations from carried (pre-scaled) dot
            const float avA = sig_raw(aA);                        // i (even) / f (odd)
            const float avB = fmaf(tA, sig_raw(aB), tC);          // g / o
            const float fv = dswap(avA);
            const float ov = dswap(avB);
            c1 = fmaf(avB, avA, fv * c1);                         // even lanes valid
            const float h1v = ov * tanh5(c1);
            const unsigned m1 = pk16(h1v, dpp2(h1v));             // (h[2q], h[2q+1])
            #define BC1(i) s1_##i = rdlu(m1, 4 * (i));
            R13(BC1)
            #undef BC1
            // ---- interleaved dots: F2(t) + F1(t+1); naA/naB seeded from f16 pre
            float naA = lo16(pw), naB = hi16(pw);
            float xA = b2A, xB = b2B;
            #define DD(i) xA  = fdot2_(wxA_##i, s1_##i, xA);  \
                          xB  = fdot2_(wxB_##i, s1_##i, xB);  \
                          naA = fdot2_(w1A_##i, s1_##i, naA); \
                          naB = fdot2_(w1B_##i, s1_##i, naB);
            R13(DD)
            #undef DD
            xs[l] = make_float2(xA, xB);
            aA = naA; aB = naB;
        };

        #pragma unroll 1
        for (int g = 0; g < SEQ / 4; ++g) {
            // prefetch rows 4(g+1)..4(g+1)+3 (clamped; tail value never used)
            const int rb = (g < SEQ / 4 - 1) ? 4 * (g + 1) : (SEQ - 4);
            const unsigned* pg = prow + (size_t)rb * 50;
            const unsigned n0 = pg[0], n1 = pg[50], n2 = pg[100], n3 = pg[150];
            float2* xs = &xsl[g & 1][0][0];
            stepA(q1, xs);
            stepA(q2, xs + 64);
            stepA(q3, xs + 128);
            stepA(n0, xs + 192);
            q1 = n1; q2 = n2; q3 = n3;
            wgbar();                                  // publish slot g&1
        }
    } else {
        // ================= wave 1: layer-2 recurrent + state + output =====
        const float boutv = HOFF ? 0.f : bout[0];
        #define LW(i) const unsigned whA_##i = ldpin(g_wh + (i)*100 + lc);      \
                      const unsigned whB_##i = ldpin(g_wh + (i)*100 + 50 + lc);
        R13(LW)
        #undef LW
        #define LWO(i) const unsigned wo_##i = HOFF ? 0u : g_wo[i];
        R13(LWO)
        #undef LWO
        #define DH(i) unsigned s2_##i = 0u;
        R13(DH)
        #undef DH
        float c2 = 0.f;
        float* h2p = HOFF ? (h2buf + (size_t)b * SEQ * UNITS + uu) : nullptr;
        const bool st = (l < 50) && !odd;

        auto stepB = [&](int t, float2 xv) {
            // wh dots from carried s2 (h2(t-1)); 2x2 partial chains for ILP
            float hA0 = 0.f, hA1 = 0.f, hB0 = 0.f, hB1 = 0.f;
            #define D0(i) hA0 = fdot2_(whA_##i, s2_##i, hA0); \
                          hB0 = fdot2_(whB_##i, s2_##i, hB0);
            #define D1(i) hA1 = fdot2_(whA_##i, s2_##i, hA1); \
                          hB1 = fdot2_(whB_##i, s2_##i, hB1);
            D0(0) D1(1) D0(2) D1(3) D0(4) D1(5) D0(6)
            D1(7) D0(8) D1(9) D0(10) D1(11) D0(12)
            #undef D0
            #undef D1
            // ---- layer-2 activations + state
            const float avA2 = sig_raw(xv.x + (hA0 + hA1));
            const float avB2 = fmaf(tA, sig_raw(xv.y + (hB0 + hB1)), tC);
            const float fv2 = dswap(avA2);
            const float ov2 = dswap(avB2);
            c2 = fmaf(avB2, avA2, fv2 * c2);
            const float h2v = ov2 * tanh5(c2);
            if (HOFF) {
                if (st) h2p[(size_t)t * UNITS] = h2v;
            }
            const unsigned m2 = pk16(h2v, dpp2(h2v));
            #define BC2(i) s2_##i = rdlu(m2, 4 * (i));
            R13(BC2)
            #undef BC2
            if (!HOFF) {
                float hp = boutv;
                #define HH(i) hp = fdot2_(wo_##i, s2_##i, hp);
                R13(HH)
                #undef HH
                if (l == 0) out[(size_t)b * SEQ + t] = sig_raw(-L2E * hp);
            }
        };

        #pragma unroll 1
        for (int g = 0; g < SEQ / 4; ++g) {
            wgbar();                                  // wait for slot g&1
            const float2* xs = &xsl[g & 1][0][0];
            // hoisted LDS reads: latency hides under first wh dot block
            const float2 xv0 = xs[lc];
            const float2 xv1 = xs[64 + lc];
            const float2 xv2 = xs[128 + lc];
            const float2 xv3 = xs[192 + lc];
            const int t = 4 * g;
            stepB(t,     xv0);
            stepB(t + 1, xv1);
            stepB(t + 2, xv2);
            stepB(t + 3, xv3);
        }
    }
}

// ---------------------------------------------------------------------------
__global__ __launch_bounds__(256)
void head_kernel(const float* __restrict__ h2buf, const float* __restrict__ Wout,
                 const float* __restrict__ bout, float* __restrict__ out) {
    __shared__ float wl[26];
    if (threadIdx.x < 25) wl[threadIdx.x] = Wout[threadIdx.x];
    if (threadIdx.x == 25) wl[25] = bout[0];
    __syncthreads();
    const int r = blockIdx.x * 256 + threadIdx.x;     // grid exactly covers BT
    const float* hp = h2buf + (size_t)r * UNITS;
    float p0 = wl[25], p1 = 0.f;
    #pragma unroll
    for (int k = 0; k < UNITS; ++k) {
        if (k & 1) p1 = fmaf(hp[k], wl[k], p1);
        else       p0 = fmaf(hp[k], wl[k], p0);
    }
    out[r] = sig_raw(-L2E * (p0 + p1));
}

// ---------------------------------------------------------------------------
extern "C" void kernel_launch(void* const* d_in, const int* in_sizes, int n_in,
                              void* d_out, int out_size, void* d_ws, size_t ws_size,
                              hipStream_t stream) {
    const float* x      = (const float*)d_in[0];
    const float* Wout   = (const float*)d_in[1];
    const float* bout   = (const float*)d_in[2];
    const float* l1_Wxi = (const float*)d_in[3];
    const float* l1_bi  = (const float*)d_in[4];
    const float* l1_Whi = (const float*)d_in[5];
    const float* l1_Wxf = (const float*)d_in[6];
    const float* l1_bf  = (const float*)d_in[7];
    const float* l1_Whf = (const float*)d_in[8];
    const float* l1_Wxc = (const float*)d_in[9];
    const float* l1_bc  = (const float*)d_in[10];
    const float* l1_Whc = (const float*)d_in[11];
    const float* l1_Wxo = (const float*)d_in[12];
    const float* l1_bo  = (const float*)d_in[13];
    const float* l1_Who = (const float*)d_in[14];
    const float* l2_Wxi = (const float*)d_in[15];
    const float* l2_bi  = (const float*)d_in[16];
    const float* l2_Whi = (const float*)d_in[17];
    const float* l2_Wxf = (const float*)d_in[18];
    const float* l2_bf  = (const float*)d_in[19];
    const float* l2_Whf = (const float*)d_in[20];
    const float* l2_Wxc = (const float*)d_in[21];
    const float* l2_bc  = (const float*)d_in[22];
    const float* l2_Whc = (const float*)d_in[23];
    const float* l2_Wxo = (const float*)d_in[24];
    const float* l2_bo  = (const float*)d_in[25];
    const float* l2_Who = (const float*)d_in[26];
    float* out = (float*)d_out;

    const size_t pre_bytes = (size_t)BT * 50 * sizeof(unsigned);  // 105 MB
    const size_t h2_bytes  = (size_t)BT * UNITS * sizeof(float);  // 52.4 MB
    unsigned* pre2h = (unsigned*)d_ws;

    prep_kernel<<<1, 128, 0, stream>>>(
        l1_Whi, l1_Whf, l1_Whc, l1_Who,
        l1_Wxi, l1_Wxf, l1_Wxc, l1_Wxo,
        l1_bi, l1_bf, l1_bc, l1_bo,
        l2_Wxi, l2_Wxf, l2_Wxc, l2_Wxo,
        l2_Whi, l2_Whf, l2_Whc, l2_Who,
        Wout);
    proj_kernel<<<BT / 512, 256, 0, stream>>>(x, pre2h);

    if (ws_size >= pre_bytes + h2_bytes) {
        float* h2buf = (float*)((char*)d_ws + pre_bytes);
        lstm_scan_kernel<true><<<BATCH, 128, 0, stream>>>(
            pre2h, l2_bi, l2_bf, l2_bc, l2_bo, bout, h2buf, out);
        head_kernel<<<BT / 256, 256, 0, stream>>>(h2buf, Wout, bout, out);
    } else {
        lstm_scan_kernel<false><<<BATCH, 128, 0, stream>>>(
            pre2h, l2_bi, l2_bf, l2_bc, l2_bo, bout, nullptr, out);
    }
}

// Round 10
// 748.667 us; speedup vs baseline: 1.0007x; 1.0007x over previous
//
#include <hip/hip_runtime.h>
#include <cstdint>
#include <cstddef>

#define UNITS 25
#define IN_DIM 64
#define BATCH 256
#define SEQ 2048
#define BT (BATCH * SEQ)
#define L2E 1.442695040888963f

typedef _Float16 h2t __attribute__((ext_vector_type(2)));

#define R13(M) M(0) M(1) M(2) M(3) M(4) M(5) M(6) M(7) M(8) M(9) M(10) M(11) M(12)

// f32 pair -> packed f16 (v_cvt_pkrtz_f16_f32)
__device__ __forceinline__ unsigned pk16(float lo, float hi) {
    return __builtin_bit_cast(unsigned, __builtin_amdgcn_cvt_pkrtz(lo, hi));
}
__device__ __forceinline__ float lo16(unsigned u) {
    return (float)__builtin_bit_cast(h2t, u).x;
}
__device__ __forceinline__ float hi16(unsigned u) {
    return (float)__builtin_bit_cast(h2t, u).y;
}
// 2-way f16 dot with f32 accumulate (v_dot2_f32_f16)
__device__ __forceinline__ float fdot2_(unsigned w, unsigned h, float c) {
#if __has_builtin(__builtin_amdgcn_fdot2)
    return __builtin_amdgcn_fdot2(__builtin_bit_cast(h2t, w),
                                  __builtin_bit_cast(h2t, h), c, false);
#else
    h2t W = __builtin_bit_cast(h2t, w), H = __builtin_bit_cast(h2t, h);
    return fmaf((float)W.x, (float)H.x, fmaf((float)W.y, (float)H.y, c));
#endif
}
// swap within lane pairs (0<->1,...): quad_perm(1,0,3,2)
__device__ __forceinline__ float dswap(float v) {
    return __int_as_float(__builtin_amdgcn_mov_dpp(__float_as_int(v), 0xB1, 0xF, 0xF, true));
}
// lane 4q+p gets lane 4q+2's value: quad_perm(2,2,2,2)
__device__ __forceinline__ float dpp2(float v) {
    return __int_as_float(__builtin_amdgcn_mov_dpp(__float_as_int(v), 0xAA, 0xF, 0xF, true));
}
__device__ __forceinline__ unsigned rdlu(unsigned v, int lane) {
    return (unsigned)__builtin_amdgcn_readlane((int)v, lane);
}
__device__ __forceinline__ float sig_raw(float a) {      // sigma from pre-scaled acc
    return __builtin_amdgcn_rcpf(1.0f + __builtin_amdgcn_exp2f(a));
}
__device__ __forceinline__ float tanh5(float c) {        // tanh(c), c unscaled
    return fmaf(2.0f, __builtin_amdgcn_rcpf(
        1.0f + __builtin_amdgcn_exp2f(-2.0f * L2E * c)), -1.0f);
}
// pinned global load: volatile asm result cannot be rematerialized by the
// compiler -> the value MUST stay resident in a VGPR.
__device__ __forceinline__ unsigned ldpin(const unsigned* p) {
    unsigned v;
    asm volatile("global_load_dword %0, %1, off\n\ts_waitcnt vmcnt(0)"
                 : "=v"(v) : "v"(p) : "memory");
    return v;
}
// producer/consumer barrier: drain LDS ops, then workgroup barrier. Raw asm
// so it is legal inside wave-uniform (but compiler-divergent) branches.
__device__ __forceinline__ void wgbar() {
    asm volatile("s_waitcnt lgkmcnt(0)\n\ts_barrier" ::: "memory");
}

// Column order (shared prep/proj/scan): c<50 = pass A (even=i, odd=f);
// c>=50 = pass B (even=c-gate[tanh], odd=o). unit u = ((c%50)>>1).
// Activation scale folded into weights/biases: tanh cols -2*L2E, else -L2E.

__device__ unsigned g_w1[13 * 100];    // layer-1 recurrent, f16 k-pairs, scaled
__device__ unsigned g_wx[13 * 100];    // layer-2 input (h1) weights
__device__ unsigned g_wh[13 * 100];    // layer-2 recurrent
__device__ unsigned g_wo[13];          // head weights, f16 pairs, unscaled
__device__ unsigned g_Wp16[100 * 32];  // proj weights: [c][kpair] f16 pairs, scaled
__device__ float    g_bp[100];         // proj bias [c], scaled

// ---------------------------------------------------------------------------
__global__ void prep_kernel(const float* __restrict__ l1_Whi, const float* __restrict__ l1_Whf,
                            const float* __restrict__ l1_Whc, const float* __restrict__ l1_Who,
                            const float* __restrict__ l1_Wxi, const float* __restrict__ l1_Wxf,
                            const float* __restrict__ l1_Wxc, const float* __restrict__ l1_Wxo,
                            const float* __restrict__ l1_bi,  const float* __restrict__ l1_bf,
                            const float* __restrict__ l1_bc,  const float* __restrict__ l1_bo,
                            const float* __restrict__ l2_Wxi, const float* __restrict__ l2_Wxf,
                            const float* __restrict__ l2_Wxc, const float* __restrict__ l2_Wxo,
                            const float* __restrict__ l2_Whi, const float* __restrict__ l2_Whf,
                            const float* __restrict__ l2_Whc, const float* __restrict__ l2_Who,
                            const float* __restrict__ Wout) {
    const int c = threadIdx.x;
    if (c < 100) {
        const int half = (c >= 50);
        const int l = half ? c - 50 : c;
        const int u = l >> 1;
        const int par = l & 1;
        const float s = (half && !par) ? (-2.0f * L2E) : (-L2E);
        const float* W1 = half ? (par ? l1_Who : l1_Whc) : (par ? l1_Whf : l1_Whi);
        const float* WX = half ? (par ? l2_Wxo : l2_Wxc) : (par ? l2_Wxf : l2_Wxi);
        const float* WH = half ? (par ? l2_Who : l2_Whc) : (par ? l2_Whf : l2_Whi);
        const float* WI = half ? (par ? l1_Wxo : l1_Wxc) : (par ? l1_Wxf : l1_Wxi);
        const float* bI = half ? (par ? l1_bo  : l1_bc)  : (par ? l1_bf  : l1_bi);
        for (int i = 0; i < 13; ++i) {
            const int k0 = 2 * i, k1 = 2 * i + 1;
            const float a1 = s * W1[k0 * UNITS + u];
            const float b1 = (k1 < UNITS) ? s * W1[k1 * UNITS + u] : 0.f;
            g_w1[i * 100 + c] = pk16(a1, b1);
            const float ax = s * WX[k0 * UNITS + u];
            const float bx = (k1 < UNITS) ? s * WX[k1 * UNITS + u] : 0.f;
            g_wx[i * 100 + c] = pk16(ax, bx);
            const float ah = s * WH[k0 * UNITS + u];
            const float bh = (k1 < UNITS) ? s * WH[k1 * UNITS + u] : 0.f;
            g_wh[i * 100 + c] = pk16(ah, bh);
        }
        for (int kp = 0; kp < 32; ++kp)
            g_Wp16[c * 32 + kp] = pk16(s * WI[(2 * kp) * UNITS + u],
                                       s * WI[(2 * kp + 1) * UNITS + u]);
        g_bp[c] = s * bI[u];
    }
    if (c == 100) {
        for (int i = 0; i < 13; ++i) {
            const int k1 = 2 * i + 1;
            g_wo[i] = pk16(Wout[2 * i], (k1 < UNITS) ? Wout[k1] : 0.f);
        }
    }
}

// ---------------------------------------------------------------------------
// proj: pre2h[row][c] = pk16(scaled pre of col c, col c+50).  2 rows/thread.
// R10: weights/bias read DIRECTLY from global with wave-uniform indices ->
// compiler emits s_load into SGPRs (scalar cache, separate pipe). This frees
// the per-CU LDS pipe, which was carrying 800 broadcast ds_read_b128 per
// wave (~12 cyc each on the shared pipe = the dominant unchanged term across
// R8/R9). LDS now holds only the output staging (R5/R8's proven coalesced
// flush, -120us). x reads are R8's direct per-thread pattern (L1 absorbs
// them; R9 proved staging is neutral). Dot order and f32 association are
// bit-identical to R8/R9 -> absmax must not move.
// ---------------------------------------------------------------------------
#define PCH 10
__global__ __launch_bounds__(256, 2)
void proj_kernel(const float* __restrict__ x, unsigned* __restrict__ pre2h) {
    __shared__ unsigned ob[2][256 * PCH];            // 20.5 KB staging
    const int tid = threadIdx.x;
    const int r0 = blockIdx.x * 512 + tid;           // 1024 blocks cover BT
    const int r1 = r0 + 256;

    uint4 xp[2][8];                                  // x rows as f16 k-pairs
    #pragma unroll
    for (int r = 0; r < 2; ++r) {
        const float4* xr = (const float4*)(x + (size_t)(r ? r1 : r0) * IN_DIM);
        #pragma unroll
        for (int j = 0; j < 8; ++j) {
            const float4 a = xr[2 * j], b = xr[2 * j + 1];
            xp[r][j] = make_uint4(pk16(a.x, a.y), pk16(a.z, a.w),
                                  pk16(b.x, b.y), pk16(b.z, b.w));
        }
    }

    #pragma unroll 1
    for (int ch = 0; ch < 50; ch += PCH) {
        #pragma unroll 1
        for (int cc = 0; cc < PCH; ++cc) {
            const int c = ch + cc;
            // uniform-address global reads -> s_load into SGPRs
            const uint4* wA = (const uint4*)(g_Wp16 + c * 32);          // col c
            const uint4* wB = (const uint4*)(g_Wp16 + (c + 50) * 32);   // col c+50
            float aA0 = g_bp[c],      aA1 = 0.f;
            float bA0 = 0.f, bA1 = 0.f;
            float aB0 = g_bp[c + 50], aB1 = 0.f, bB0 = 0.f, bB1 = 0.f;
            float cA0 = g_bp[c],      cA1 = 0.f, dA0 = 0.f, dA1 = 0.f; // row1
            float cB0 = g_bp[c + 50], cB1 = 0.f, dB0 = 0.f, dB1 = 0.f;
            #pragma unroll
            for (int j = 0; j < 8; ++j) {
                const uint4 wa = wA[j], wb = wB[j];
                const uint4 x0 = xp[0][j], x1 = xp[1][j];
                aA0 = fdot2_(wa.x, x0.x, aA0); bA0 = fdot2_(wa.y, x0.y, bA0);
                aA1 = fdot2_(wa.z, x0.z, aA1); bA1 = fdot2_(wa.w, x0.w, bA1);
                aB0 = fdot2_(wb.x, x0.x, aB0); bB0 = fdot2_(wb.y, x0.y, bB0);
                aB1 = fdot2_(wb.z, x0.z, aB1); bB1 = fdot2_(wb.w, x0.w, bB1);
                cA0 = fdot2_(wa.x, x1.x, cA0); dA0 = fdot2_(wa.y, x1.y, dA0);
                cA1 = fdot2_(wa.z, x1.z, cA1); dA1 = fdot2_(wa.w, x1.w, dA1);
                cB0 = fdot2_(wb.x, x1.x, cB0); dB0 = fdot2_(wb.y, x1.y, dB0);
                cB1 = fdot2_(wb.z, x1.z, cB1); dB1 = fdot2_(wb.w, x1.w, dB1);
            }
            ob[0][tid * PCH + cc] = pk16((aA0 + aA1) + (bA0 + bA1),
                                         (aB0 + aB1) + (bB0 + bB1));
            ob[1][tid * PCH + cc] = pk16((cA0 + cA1) + (dA0 + dA1),
                                         (cB0 + cB1) + (dB0 + dB1));
        }
        __syncthreads();
        #pragma unroll
        for (int g = 0; g < 2; ++g) {
            const size_t rowbase = ((size_t)blockIdx.x * 512 + g * 256) * 50 + ch;
            #pragma unroll
            for (int k = 0; k < PCH; ++k) {
                const int i = tid + k * 256;
                const int row = i / PCH;
                const int c2 = i - row * PCH;
                pre2h[rowbase + (size_t)row * 50 + c2] = ob[g][i];
            }
        }
        __syncthreads();
    }
}

// ---------------------------------------------------------------------------
// scan: 1 batch element per block, TWO waves on two SIMDs, pipelined
// (R1 structure, proven 431-444us; R2/R4 restructures both regressed):
//   wave0 = layer-1 (act + w1 dots + wx dots)  -> xA,xB into LDS slot
//   wave1 = layer-2 (wh dots + act + h2 store), one group (4 steps) behind.
// ---------------------------------------------------------------------------
template<bool HOFF>
__global__ __attribute__((amdgpu_waves_per_eu(1, 1))) __launch_bounds__(128)
void lstm_scan_kernel(const unsigned* __restrict__ pre2h,
                      const float* __restrict__ l2_bi, const float* __restrict__ l2_bf,
                      const float* __restrict__ l2_bc, const float* __restrict__ l2_bo,
                      const float* __restrict__ bout,
                      float* __restrict__ h2buf, float* __restrict__ out) {
    __shared__ float2 xsl[2][4][64];                 // [slot][sub-step][lane]
    const int tid = threadIdx.x;
    const int l   = tid & 63;
    const int b   = blockIdx.x;
    const int lc  = (l < 50) ? l : 49;   // lanes 50..63 compute junk, never read
    const int uu  = lc >> 1;
    const bool odd = (l & 1);
    // pass-B activation per parity: even lane -> tanh form, odd -> sigmoid
    const float tA = odd ? 1.0f : 2.0f;
    const float tC = odd ? 0.0f : -1.0f;

    if (tid < 64) {
        // ================= wave 0: layer 1 + layer-2 input dots ===========
        const float b2A = (odd ? l2_bf[uu] : l2_bi[uu]) * (-L2E);
        const float b2B = odd ? (l2_bo[uu] * (-L2E)) : (l2_bc[uu] * (-2.0f * L2E));
        #define LW(i) const unsigned w1A_##i = ldpin(g_w1 + (i)*100 + lc);      \
                      const unsigned w1B_##i = ldpin(g_w1 + (i)*100 + 50 + lc); \
                      const unsigned wxA_##i = ldpin(g_wx + (i)*100 + lc);      \
                      const unsigned wxB_##i = ldpin(g_wx + (i)*100 + 50 + lc);
        R13(LW)
        #undef LW
        #define DH(i) unsigned s1_##i = 0u;
        R13(DH)
        #undef DH
        float c1 = 0.f;

        const unsigned* prow = pre2h + (size_t)b * SEQ * 50 + lc;
        // carried F1 accumulators, primed from pre(0) (h1(-1)=0)
        const unsigned p0 = prow[0];
        float aA = lo16(p0), aB = hi16(p0);
        unsigned q1 = prow[50], q2 = prow[100], q3 = prow[150];

        auto stepA = [&](unsigned pw, float2* xs) {
            // ---- layer-1 activations from carried (pre-scaled) dot
            const float avA = sig_raw(aA);                        // i (even) / f (odd)
            const float avB = fmaf(tA, sig_raw(aB), tC);          // g / o
            const float fv = dswap(avA);
            const float ov = dswap(avB);
            c1 = fmaf(avB, avA, fv * c1);                         // even lanes valid
            const float h1v = ov * tanh5(c1);
            const unsigned m1 = pk16(h1v, dpp2(h1v));             // (h[2q], h[2q+1])
            #define BC1(i) s1_##i = rdlu(m1, 4 * (i));
            R13(BC1)
            #undef BC1
            // ---- interleaved dots: F2(t) + F1(t+1); naA/naB seeded from f16 pre
            float naA = lo16(pw), naB = hi16(pw);
            float xA = b2A, xB = b2B;
            #define DD(i) xA  = fdot2_(wxA_##i, s1_##i, xA);  \
                          xB  = fdot2_(wxB_##i, s1_##i, xB);  \
                          naA = fdot2_(w1A_##i, s1_##i, naA); \
                          naB = fdot2_(w1B_##i, s1_##i, naB);
            R13(DD)
            #undef DD
            xs[l] = make_float2(xA, xB);
            aA = naA; aB = naB;
        };

        #pragma unroll 1
        for (int g = 0; g < SEQ / 4; ++g) {
            // prefetch rows 4(g+1)..4(g+1)+3 (clamped; tail value never used)
            const int rb = (g < SEQ / 4 - 1) ? 4 * (g + 1) : (SEQ - 4);
            const unsigned* pg = prow + (size_t)rb * 50;
            const unsigned n0 = pg[0], n1 = pg[50], n2 = pg[100], n3 = pg[150];
            float2* xs = &xsl[g & 1][0][0];
            stepA(q1, xs);
            stepA(q2, xs + 64);
            stepA(q3, xs + 128);
            stepA(n0, xs + 192);
            q1 = n1; q2 = n2; q3 = n3;
            wgbar();                                  // publish slot g&1
        }
    } else {
        // ================= wave 1: layer-2 recurrent + state + output =====
        const float boutv = HOFF ? 0.f : bout[0];
        #define LW(i) const unsigned whA_##i = ldpin(g_wh + (i)*100 + lc);      \
                      const unsigned whB_##i = ldpin(g_wh + (i)*100 + 50 + lc);
        R13(LW)
        #undef LW
        #define LWO(i) const unsigned wo_##i = HOFF ? 0u : g_wo[i];
        R13(LWO)
        #undef LWO
        #define DH(i) unsigned s2_##i = 0u;
        R13(DH)
        #undef DH
        float c2 = 0.f;
        float* h2p = HOFF ? (h2buf + (size_t)b * SEQ * UNITS + uu) : nullptr;
        const bool st = (l < 50) && !odd;

        auto stepB = [&](int t, float2 xv) {
            // wh dots from carried s2 (h2(t-1)); 2x2 partial chains for ILP
            float hA0 = 0.f, hA1 = 0.f, hB0 = 0.f, hB1 = 0.f;
            #define D0(i) hA0 = fdot2_(whA_##i, s2_##i, hA0); \
                          hB0 = fdot2_(whB_##i, s2_##i, hB0);
            #define D1(i) hA1 = fdot2_(whA_##i, s2_##i, hA1); \
                          hB1 = fdot2_(whB_##i, s2_##i, hB1);
            D0(0) D1(1) D0(2) D1(3) D0(4) D1(5) D0(6)
            D1(7) D0(8) D1(9) D0(10) D1(11) D0(12)
            #undef D0
            #undef D1
            // ---- layer-2 activations + state
            const float avA2 = sig_raw(xv.x + (hA0 + hA1));
            const float avB2 = fmaf(tA, sig_raw(xv.y + (hB0 + hB1)), tC);
            const float fv2 = dswap(avA2);
            const float ov2 = dswap(avB2);
            c2 = fmaf(avB2, avA2, fv2 * c2);
            const float h2v = ov2 * tanh5(c2);
            if (HOFF) {
                if (st) h2p[(size_t)t * UNITS] = h2v;
            }
            const unsigned m2 = pk16(h2v, dpp2(h2v));
            #define BC2(i) s2_##i = rdlu(m2, 4 * (i));
            R13(BC2)
            #undef BC2
            if (!HOFF) {
                float hp = boutv;
                #define HH(i) hp = fdot2_(wo_##i, s2_##i, hp);
                R13(HH)
                #undef HH
                if (l == 0) out[(size_t)b * SEQ + t] = sig_raw(-L2E * hp);
            }
        };

        #pragma unroll 1
        for (int g = 0; g < SEQ / 4; ++g) {
            wgbar();                                  // wait for slot g&1
            const float2* xs = &xsl[g & 1][0][0];
            // hoisted LDS reads: latency hides under first wh dot block
            const float2 xv0 = xs[lc];
            const float2 xv1 = xs[64 + lc];
            const float2 xv2 = xs[128 + lc];
            const float2 xv3 = xs[192 + lc];
            const int t = 4 * g;
            stepB(t,     xv0);
            stepB(t + 1, xv1);
            stepB(t + 2, xv2);
            stepB(t + 3, xv3);
        }
    }
}

// ---------------------------------------------------------------------------
__global__ __launch_bounds__(256)
void head_kernel(const float* __restrict__ h2buf, const float* __restrict__ Wout,
                 const float* __restrict__ bout, float* __restrict__ out) {
    __shared__ float wl[26];
    if (threadIdx.x < 25) wl[threadIdx.x] = Wout[threadIdx.x];
    if (threadIdx.x == 25) wl[25] = bout[0];
    __syncthreads();
    const int r = blockIdx.x * 256 + threadIdx.x;     // grid exactly covers BT
    const float* hp = h2buf + (size_t)r * UNITS;
    float p0 = wl[25], p1 = 0.f;
    #pragma unroll
    for (int k = 0; k < UNITS; ++k) {
        if (k & 1) p1 = fmaf(hp[k], wl[k], p1);
        else       p0 = fmaf(hp[k], wl[k], p0);
    }
    out[r] = sig_raw(-L2E * (p0 + p1));
}

// ---------------------------------------------------------------------------
extern "C" void kernel_launch(void* const* d_in, const int* in_sizes, int n_in,
                              void* d_out, int out_size, void* d_ws, size_t ws_size,
                              hipStream_t stream) {
    const float* x      = (const float*)d_in[0];
    const float* Wout   = (const float*)d_in[1];
    const float* bout   = (const float*)d_in[2];
    const float* l1_Wxi = (const float*)d_in[3];
    const float* l1_bi  = (const float*)d_in[4];
    const float* l1_Whi = (const float*)d_in[5];
    const float* l1_Wxf = (const float*)d_in[6];
    const float* l1_bf  = (const float*)d_in[7];
    const float* l1_Whf = (const float*)d_in[8];
    const float* l1_Wxc = (const float*)d_in[9];
    const float* l1_bc  = (const float*)d_in[10];
    const float* l1_Whc = (const float*)d_in[11];
    const float* l1_Wxo = (const float*)d_in[12];
    const float* l1_bo  = (const float*)d_in[13];
    const float* l1_Who = (const float*)d_in[14];
    const float* l2_Wxi = (const float*)d_in[15];
    const float* l2_bi  = (const float*)d_in[16];
    const float* l2_Whi = (const float*)d_in[17];
    const float* l2_Wxf = (const float*)d_in[18];
    const float* l2_bf  = (const float*)d_in[19];
    const float* l2_Whf = (const float*)d_in[20];
    const float* l2_Wxc = (const float*)d_in[21];
    const float* l2_bc  = (const float*)d_in[22];
    const float* l2_Whc = (const float*)d_in[23];
    const float* l2_Wxo = (const float*)d_in[24];
    const float* l2_bo  = (const float*)d_in[25];
    const float* l2_Who = (const float*)d_in[26];
    float* out = (float*)d_out;

    const size_t pre_bytes = (size_t)BT * 50 * sizeof(unsigned);  // 105 MB
    const size_t h2_bytes  = (size_t)BT * UNITS * sizeof(float);  // 52.4 MB
    unsigned* pre2h = (unsigned*)d_ws;

    prep_kernel<<<1, 128, 0, stream>>>(
        l1_Whi, l1_Whf, l1_Whc, l1_Who,
        l1_Wxi, l1_Wxf, l1_Wxc, l1_Wxo,
        l1_bi, l1_bf, l1_bc, l1_bo,
        l2_Wxi, l2_Wxf, l2_Wxc, l2_Wxo,
        l2_Whi, l2_Whf, l2_Whc, l2_Who,
        Wout);
    proj_kernel<<<BT / 512, 256, 0, stream>>>(x, pre2h);

    if (ws_size >= pre_bytes + h2_bytes) {
        float* h2buf = (float*)((char*)d_ws + pre_bytes);
        lstm_scan_kernel<true><<<BATCH, 128, 0, stream>>>(
            pre2h, l2_bi, l2_bf, l2_bc, l2_bo, bout, h2buf, out);
        head_kernel<<<BT / 256, 256, 0, stream>>>(h2buf, Wout, bout, out);
    } else {
        lstm_scan_kernel<false><<<BATCH, 128, 0, stream>>>(
            pre2h, l2_bi, l2_bf, l2_bc, l2_bo, bout, nullptr, out);
    }
}

// Round 11
// 699.651 us; speedup vs baseline: 1.0708x; 1.0701x over previous
//
#include <hip/hip_runtime.h>
#include <cstdint>
#include <cstddef>

#define UNITS 25
#define IN_DIM 64
#define BATCH 256
#define SEQ 2048
#define BT (BATCH * SEQ)
#define L2E 1.442695040888963f

typedef _Float16 h2t __attribute__((ext_vector_type(2)));
typedef _Float16 f16x8 __attribute__((ext_vector_type(8)));
typedef float f32x4 __attribute__((ext_vector_type(4)));

#define R13(M) M(0) M(1) M(2) M(3) M(4) M(5) M(6) M(7) M(8) M(9) M(10) M(11) M(12)

// f32 pair -> packed f16 (v_cvt_pkrtz_f16_f32)
__device__ __forceinline__ unsigned pk16(float lo, float hi) {
    return __builtin_bit_cast(unsigned, __builtin_amdgcn_cvt_pkrtz(lo, hi));
}
__device__ __forceinline__ float lo16(unsigned u) {
    return (float)__builtin_bit_cast(h2t, u).x;
}
__device__ __forceinline__ float hi16(unsigned u) {
    return (float)__builtin_bit_cast(h2t, u).y;
}
// 2-way f16 dot with f32 accumulate (v_dot2_f32_f16)
__device__ __forceinline__ float fdot2_(unsigned w, unsigned h, float c) {
#if __has_builtin(__builtin_amdgcn_fdot2)
    return __builtin_amdgcn_fdot2(__builtin_bit_cast(h2t, w),
                                  __builtin_bit_cast(h2t, h), c, false);
#else
    h2t W = __builtin_bit_cast(h2t, w), H = __builtin_bit_cast(h2t, h);
    return fmaf((float)W.x, (float)H.x, fmaf((float)W.y, (float)H.y, c));
#endif
}
// swap within lane pairs (0<->1,...): quad_perm(1,0,3,2)
__device__ __forceinline__ float dswap(float v) {
    return __int_as_float(__builtin_amdgcn_mov_dpp(__float_as_int(v), 0xB1, 0xF, 0xF, true));
}
// lane 4q+p gets lane 4q+2's value: quad_perm(2,2,2,2)
__device__ __forceinline__ float dpp2(float v) {
    return __int_as_float(__builtin_amdgcn_mov_dpp(__float_as_int(v), 0xAA, 0xF, 0xF, true));
}
__device__ __forceinline__ unsigned rdlu(unsigned v, int lane) {
    return (unsigned)__builtin_amdgcn_readlane((int)v, lane);
}
__device__ __forceinline__ float sig_raw(float a) {      // sigma from pre-scaled acc
    return __builtin_amdgcn_rcpf(1.0f + __builtin_amdgcn_exp2f(a));
}
__device__ __forceinline__ float tanh5(float c) {        // tanh(c), c unscaled
    return fmaf(2.0f, __builtin_amdgcn_rcpf(
        1.0f + __builtin_amdgcn_exp2f(-2.0f * L2E * c)), -1.0f);
}
// pinned global load: volatile asm result cannot be rematerialized by the
// compiler -> the value MUST stay resident in a VGPR.
__device__ __forceinline__ unsigned ldpin(const unsigned* p) {
    unsigned v;
    asm volatile("global_load_dword %0, %1, off\n\ts_waitcnt vmcnt(0)"
                 : "=v"(v) : "v"(p) : "memory");
    return v;
}
// producer/consumer barrier: drain LDS ops, then workgroup barrier. Raw asm
// so it is legal inside wave-uniform (but compiler-divergent) branches.
__device__ __forceinline__ void wgbar() {
    asm volatile("s_waitcnt lgkmcnt(0)\n\ts_barrier" ::: "memory");
}

// Column order (shared prep/proj/scan): c<50 = pass A (even=i, odd=f);
// c>=50 = pass B (even=c-gate[tanh], odd=o). unit u = ((c%50)>>1).
// Activation scale folded into weights/biases: tanh cols -2*L2E, else -L2E.

__device__ unsigned g_w1[13 * 100];    // layer-1 recurrent, f16 k-pairs, scaled
__device__ unsigned g_wx[13 * 100];    // layer-2 input (h1) weights
__device__ unsigned g_wh[13 * 100];    // layer-2 recurrent
__device__ unsigned g_wo[13];          // head weights, f16 pairs, unscaled
__device__ unsigned g_Wp16[100 * 32];  // proj weights: [c][kpair] f16 pairs, scaled
__device__ float    g_bp[100];         // proj bias [c], scaled

// ---------------------------------------------------------------------------
__global__ void prep_kernel(const float* __restrict__ l1_Whi, const float* __restrict__ l1_Whf,
                            const float* __restrict__ l1_Whc, const float* __restrict__ l1_Who,
                            const float* __restrict__ l1_Wxi, const float* __restrict__ l1_Wxf,
                            const float* __restrict__ l1_Wxc, const float* __restrict__ l1_Wxo,
                            const float* __restrict__ l1_bi,  const float* __restrict__ l1_bf,
                            const float* __restrict__ l1_bc,  const float* __restrict__ l1_bo,
                            const float* __restrict__ l2_Wxi, const float* __restrict__ l2_Wxf,
                            const float* __restrict__ l2_Wxc, const float* __restrict__ l2_Wxo,
                            const float* __restrict__ l2_Whi, const float* __restrict__ l2_Whf,
                            const float* __restrict__ l2_Whc, const float* __restrict__ l2_Who,
                            const float* __restrict__ Wout) {
    const int c = threadIdx.x;
    if (c < 100) {
        const int half = (c >= 50);
        const int l = half ? c - 50 : c;
        const int u = l >> 1;
        const int par = l & 1;
        const float s = (half && !par) ? (-2.0f * L2E) : (-L2E);
        const float* W1 = half ? (par ? l1_Who : l1_Whc) : (par ? l1_Whf : l1_Whi);
        const float* WX = half ? (par ? l2_Wxo : l2_Wxc) : (par ? l2_Wxf : l2_Wxi);
        const float* WH = half ? (par ? l2_Who : l2_Whc) : (par ? l2_Whf : l2_Whi);
        const float* WI = half ? (par ? l1_Wxo : l1_Wxc) : (par ? l1_Wxf : l1_Wxi);
        const float* bI = half ? (par ? l1_bo  : l1_bc)  : (par ? l1_bf  : l1_bi);
        for (int i = 0; i < 13; ++i) {
            const int k0 = 2 * i, k1 = 2 * i + 1;
            const float a1 = s * W1[k0 * UNITS + u];
            const float b1 = (k1 < UNITS) ? s * W1[k1 * UNITS + u] : 0.f;
            g_w1[i * 100 + c] = pk16(a1, b1);
            const float ax = s * WX[k0 * UNITS + u];
            const float bx = (k1 < UNITS) ? s * WX[k1 * UNITS + u] : 0.f;
            g_wx[i * 100 + c] = pk16(ax, bx);
            const float ah = s * WH[k0 * UNITS + u];
            const float bh = (k1 < UNITS) ? s * WH[k1 * UNITS + u] : 0.f;
            g_wh[i * 100 + c] = pk16(ah, bh);
        }
        for (int kp = 0; kp < 32; ++kp)
            g_Wp16[c * 32 + kp] = pk16(s * WI[(2 * kp) * UNITS + u],
                                       s * WI[(2 * kp + 1) * UNITS + u]);
        g_bp[c] = s * bI[u];
    }
    if (c == 100) {
        for (int i = 0; i < 13; ++i) {
            const int k1 = 2 * i + 1;
            g_wo[i] = pk16(Wout[2 * i], (k1 < UNITS) ? Wout[k1] : 0.f);
        }
    }
}

// ---------------------------------------------------------------------------
// proj R11: MFMA rewrite. C[BT x 100] = X[BT x 64] . W[64 x 100] via
// mfma_f32_16x16x32_f16: 64 rows/block, wave w owns M-tile rows 16w..16w+15;
// 7 N-tiles x 2 K-steps = 14 MFMA/wave. ~30x fewer instructions than the
// fdot2 version (attacks every pipe at once -- decisive test of whether proj
// is the persistent ~300us gap). Fragment layouts:
//   A: lane l holds X[row=l&15][k=8*(l>>4)+j], j=0..7  (4 dwords of k-pairs)
//   B: lane l holds W[k=8*(l>>4)+j][col=l&15]          (g_Wp16 k-pair order)
//   D: col=lane&15, row=(lane>>4)*4+reg                (m89-verified)
// f16 input values identical to the fdot2 version (same pk16 conversions,
// same folded scale); only f32 accumulation order changes. Bias added in the
// pack stage. Output stores are fully contiguous dwords.
// ---------------------------------------------------------------------------
__global__ __launch_bounds__(256)
void proj_kernel(const float* __restrict__ x, unsigned* __restrict__ pre2h) {
    __shared__ unsigned xs[64 * 36];      // x rows as f16 k-pairs, pad 36
    __shared__ unsigned wls[100 * 36];    // weights, pad 36
    __shared__ float bls[100];
    __shared__ float of32[64 * 112];      // f32 pre-activations, pad 112
    const int tid = threadIdx.x;

    // weights + bias -> LDS (re-padded from g_Wp16's dense 32/row)
    for (int i = tid; i < 3200; i += 256)
        wls[(i >> 5) * 36 + (i & 31)] = g_Wp16[i];
    if (tid < 100) bls[tid] = g_bp[tid];

    // x stage: 64 rows, fully coalesced float4 loads -> f16 pairs in LDS
    const float4* xg = (const float4*)(x + (size_t)blockIdx.x * 64 * IN_DIM);
    #pragma unroll
    for (int k = 0; k < 4; ++k) {
        const int q = tid + (k << 8);          // float4 index 0..1023
        const float4 a = xg[q];
        const int row = q >> 4;                // 16 float4 per row
        const int fc = q & 15;
        *(uint2*)&xs[row * 36 + 2 * fc] = make_uint2(pk16(a.x, a.y), pk16(a.z, a.w));
    }
    __syncthreads();

    const int w = tid >> 6, l = tid & 63;
    const int lr = l & 15, lg = l >> 4;        // row-in-tile, k-group
    // A fragments: rows 16w+lr, K-steps 0/1 (k-pairs 16*kk + 4*lg .. +3)
    const unsigned* xrow = xs + (16 * w + lr) * 36;
    const f16x8 a0 = __builtin_bit_cast(f16x8, *(const uint4*)(xrow + 4 * lg));
    const f16x8 a1 = __builtin_bit_cast(f16x8, *(const uint4*)(xrow + 16 + 4 * lg));

    #pragma unroll
    for (int nt = 0; nt < 7; ++nt) {
        const int c = nt * 16 + lr;            // output column
        const int cl = (c < 100) ? c : 99;     // clamp loads; results discarded
        const unsigned* wrow = wls + cl * 36;
        const f16x8 b0 = __builtin_bit_cast(f16x8, *(const uint4*)(wrow + 4 * lg));
        const f16x8 b1 = __builtin_bit_cast(f16x8, *(const uint4*)(wrow + 16 + 4 * lg));
        f32x4 acc = {0.f, 0.f, 0.f, 0.f};
        acc = __builtin_amdgcn_mfma_f32_16x16x32_f16(a0, b0, acc, 0, 0, 0);
        acc = __builtin_amdgcn_mfma_f32_16x16x32_f16(a1, b1, acc, 0, 0, 0);
        if (c < 100) {
            #pragma unroll
            for (int r = 0; r < 4; ++r)
                of32[(16 * w + 4 * lg + r) * 112 + c] = acc[r];
        }
    }
    __syncthreads();

    // bias + pack + fully-contiguous store (block's 3200 dwords are linear)
    const size_t base = (size_t)blockIdx.x * 64 * 50;
    #pragma unroll
    for (int k = 0; k < 13; ++k) {
        const int i = tid + (k << 8);
        if (i < 3200) {
            const int row = i / 50;
            const int d = i - row * 50;
            const float pa = of32[row * 112 + d] + bls[d];
            const float pb = of32[row * 112 + d + 50] + bls[d + 50];
            pre2h[base + i] = pk16(pa, pb);
        }
    }
}

// ---------------------------------------------------------------------------
// scan: 1 batch element per block, TWO waves on two SIMDs, pipelined
// (R1 structure, proven 429-444us; R2/R4 restructures both regressed):
//   wave0 = layer-1 (act + w1 dots + wx dots)  -> xA,xB into LDS slot
//   wave1 = layer-2 (wh dots + act + h2 store), one group (4 steps) behind.
// ---------------------------------------------------------------------------
template<bool HOFF>
__global__ __attribute__((amdgpu_waves_per_eu(1, 1))) __launch_bounds__(128)
void lstm_scan_kernel(const unsigned* __restrict__ pre2h,
                      const float* __restrict__ l2_bi, const float* __restrict__ l2_bf,
                      const float* __restrict__ l2_bc, const float* __restrict__ l2_bo,
                      const float* __restrict__ bout,
                      float* __restrict__ h2buf, float* __restrict__ out) {
    __shared__ float2 xsl[2][4][64];                 // [slot][sub-step][lane]
    const int tid = threadIdx.x;
    const int l   = tid & 63;
    const int b   = blockIdx.x;
    const int lc  = (l < 50) ? l : 49;   // lanes 50..63 compute junk, never read
    const int uu  = lc >> 1;
    const bool odd = (l & 1);
    // pass-B activation per parity: even lane -> tanh form, odd -> sigmoid
    const float tA = odd ? 1.0f : 2.0f;
    const float tC = odd ? 0.0f : -1.0f;

    if (tid < 64) {
        // ================= wave 0: layer 1 + layer-2 input dots ===========
        const float b2A = (odd ? l2_bf[uu] : l2_bi[uu]) * (-L2E);
        const float b2B = odd ? (l2_bo[uu] * (-L2E)) : (l2_bc[uu] * (-2.0f * L2E));
        #define LW(i) const unsigned w1A_##i = ldpin(g_w1 + (i)*100 + lc);      \
                      const unsigned w1B_##i = ldpin(g_w1 + (i)*100 + 50 + lc); \
                      const unsigned wxA_##i = ldpin(g_wx + (i)*100 + lc);      \
                      const unsigned wxB_##i = ldpin(g_wx + (i)*100 + 50 + lc);
        R13(LW)
        #undef LW
        #define DH(i) unsigned s1_##i = 0u;
        R13(DH)
        #undef DH
        float c1 = 0.f;

        const unsigned* prow = pre2h + (size_t)b * SEQ * 50 + lc;
        // carried F1 accumulators, primed from pre(0) (h1(-1)=0)
        const unsigned p0 = prow[0];
        float aA = lo16(p0), aB = hi16(p0);
        unsigned q1 = prow[50], q2 = prow[100], q3 = prow[150];

        auto stepA = [&](unsigned pw, float2* xs) {
            // ---- layer-1 activations from carried (pre-scaled) dot
            const float avA = sig_raw(aA);                        // i (even) / f (odd)
            const float avB = fmaf(tA, sig_raw(aB), tC);          // g / o
            const float fv = dswap(avA);
            const float ov = dswap(avB);
            c1 = fmaf(avB, avA, fv * c1);                         // even lanes valid
            const float h1v = ov * tanh5(c1);
            const unsigned m1 = pk16(h1v, dpp2(h1v));             // (h[2q], h[2q+1])
            #define BC1(i) s1_##i = rdlu(m1, 4 * (i));
            R13(BC1)
            #undef BC1
            // ---- interleaved dots: F2(t) + F1(t+1); naA/naB seeded from f16 pre
            float naA = lo16(pw), naB = hi16(pw);
            float xA = b2A, xB = b2B;
            #define DD(i) xA  = fdot2_(wxA_##i, s1_##i, xA);  \
                          xB  = fdot2_(wxB_##i, s1_##i, xB);  \
                          naA = fdot2_(w1A_##i, s1_##i, naA); \
                          naB = fdot2_(w1B_##i, s1_##i, naB);
            R13(DD)
            #undef DD
            xs[l] = make_float2(xA, xB);
            aA = naA; aB = naB;
        };

        #pragma unroll 1
        for (int g = 0; g < SEQ / 4; ++g) {
            // prefetch rows 4(g+1)..4(g+1)+3 (clamped; tail value never used)
            const int rb = (g < SEQ / 4 - 1) ? 4 * (g + 1) : (SEQ - 4);
            const unsigned* pg = prow + (size_t)rb * 50;
            const unsigned n0 = pg[0], n1 = pg[50], n2 = pg[100], n3 = pg[150];
            float2* xs = &xsl[g & 1][0][0];
            stepA(q1, xs);
            stepA(q2, xs + 64);
            stepA(q3, xs + 128);
            stepA(n0, xs + 192);
            q1 = n1; q2 = n2; q3 = n3;
            wgbar();                                  // publish slot g&1
        }
    } else {
        // ================= wave 1: layer-2 recurrent + state + output =====
        const float boutv = HOFF ? 0.f : bout[0];
        #define LW(i) const unsigned whA_##i = ldpin(g_wh + (i)*100 + lc);      \
                      const unsigned whB_##i = ldpin(g_wh + (i)*100 + 50 + lc);
        R13(LW)
        #undef LW
        #define LWO(i) const unsigned wo_##i = HOFF ? 0u : g_wo[i];
        R13(LWO)
        #undef LWO
        #define DH(i) unsigned s2_##i = 0u;
        R13(DH)
        #undef DH
        float c2 = 0.f;
        float* h2p = HOFF ? (h2buf + (size_t)b * SEQ * UNITS + uu) : nullptr;
        const bool st = (l < 50) && !odd;

        auto stepB = [&](int t, float2 xv) {
            // wh dots from carried s2 (h2(t-1)); 2x2 partial chains for ILP
            float hA0 = 0.f, hA1 = 0.f, hB0 = 0.f, hB1 = 0.f;
            #define D0(i) hA0 = fdot2_(whA_##i, s2_##i, hA0); \
                          hB0 = fdot2_(whB_##i, s2_##i, hB0);
            #define D1(i) hA1 = fdot2_(whA_##i, s2_##i, hA1); \
                          hB1 = fdot2_(whB_##i, s2_##i, hB1);
            D0(0) D1(1) D0(2) D1(3) D0(4) D1(5) D0(6)
            D1(7) D0(8) D1(9) D0(10) D1(11) D0(12)
            #undef D0
            #undef D1
            // ---- layer-2 activations + state
            const float avA2 = sig_raw(xv.x + (hA0 + hA1));
            const float avB2 = fmaf(tA, sig_raw(xv.y + (hB0 + hB1)), tC);
            const float fv2 = dswap(avA2);
            const float ov2 = dswap(avB2);
            c2 = fmaf(avB2, avA2, fv2 * c2);
            const float h2v = ov2 * tanh5(c2);
            if (HOFF) {
                if (st) h2p[(size_t)t * UNITS] = h2v;
            }
            const unsigned m2 = pk16(h2v, dpp2(h2v));
            #define BC2(i) s2_##i = rdlu(m2, 4 * (i));
            R13(BC2)
            #undef BC2
            if (!HOFF) {
                float hp = boutv;
                #define HH(i) hp = fdot2_(wo_##i, s2_##i, hp);
                R13(HH)
                #undef HH
                if (l == 0) out[(size_t)b * SEQ + t] = sig_raw(-L2E * hp);
            }
        };

        #pragma unroll 1
        for (int g = 0; g < SEQ / 4; ++g) {
            wgbar();                                  // wait for slot g&1
            const float2* xs = &xsl[g & 1][0][0];
            // hoisted LDS reads: latency hides under first wh dot block
            const float2 xv0 = xs[lc];
            const float2 xv1 = xs[64 + lc];
            const float2 xv2 = xs[128 + lc];
            const float2 xv3 = xs[192 + lc];
            const int t = 4 * g;
            stepB(t,     xv0);
            stepB(t + 1, xv1);
            stepB(t + 2, xv2);
            stepB(t + 3, xv3);
        }
    }
}

// ---------------------------------------------------------------------------
__global__ __launch_bounds__(256)
void head_kernel(const float* __restrict__ h2buf, const float* __restrict__ Wout,
                 const float* __restrict__ bout, float* __restrict__ out) {
    __shared__ float wl[26];
    if (threadIdx.x < 25) wl[threadIdx.x] = Wout[threadIdx.x];
    if (threadIdx.x == 25) wl[25] = bout[0];
    __syncthreads();
    const int r = blockIdx.x * 256 + threadIdx.x;     // grid exactly covers BT
    const float* hp = h2buf + (size_t)r * UNITS;
    float p0 = wl[25], p1 = 0.f;
    #pragma unroll
    for (int k = 0; k < UNITS; ++k) {
        if (k & 1) p1 = fmaf(hp[k], wl[k], p1);
        else       p0 = fmaf(hp[k], wl[k], p0);
    }
    out[r] = sig_raw(-L2E * (p0 + p1));
}

// ---------------------------------------------------------------------------
extern "C" void kernel_launch(void* const* d_in, const int* in_sizes, int n_in,
                              void* d_out, int out_size, void* d_ws, size_t ws_size,
                              hipStream_t stream) {
    const float* x      = (const float*)d_in[0];
    const float* Wout   = (const float*)d_in[1];
    const float* bout   = (const float*)d_in[2];
    const float* l1_Wxi = (const float*)d_in[3];
    const float* l1_bi  = (const float*)d_in[4];
    const float* l1_Whi = (const float*)d_in[5];
    const float* l1_Wxf = (const float*)d_in[6];
    const float* l1_bf  = (const float*)d_in[7];
    const float* l1_Whf = (const float*)d_in[8];
    const float* l1_Wxc = (const float*)d_in[9];
    const float* l1_bc  = (const float*)d_in[10];
    const float* l1_Whc = (const float*)d_in[11];
    const float* l1_Wxo = (const float*)d_in[12];
    const float* l1_bo  = (const float*)d_in[13];
    const float* l1_Who = (const float*)d_in[14];
    const float* l2_Wxi = (const float*)d_in[15];
    const float* l2_bi  = (const float*)d_in[16];
    const float* l2_Whi = (const float*)d_in[17];
    const float* l2_Wxf = (const float*)d_in[18];
    const float* l2_bf  = (const float*)d_in[19];
    const float* l2_Whf = (const float*)d_in[20];
    const float* l2_Wxc = (const float*)d_in[21];
    const float* l2_bc  = (const float*)d_in[22];
    const float* l2_Whc = (const float*)d_in[23];
    const float* l2_Wxo = (const float*)d_in[24];
    const float* l2_bo  = (const float*)d_in[25];
    const float* l2_Who = (const float*)d_in[26];
    float* out = (float*)d_out;

    const size_t pre_bytes = (size_t)BT * 50 * sizeof(unsigned);  // 105 MB
    const size_t h2_bytes  = (size_t)BT * UNITS * sizeof(float);  // 52.4 MB
    unsigned* pre2h = (unsigned*)d_ws;

    prep_kernel<<<1, 128, 0, stream>>>(
        l1_Whi, l1_Whf, l1_Whc, l1_Who,
        l1_Wxi, l1_Wxf, l1_Wxc, l1_Wxo,
        l1_bi, l1_bf, l1_bc, l1_bo,
        l2_Wxi, l2_Wxf, l2_Wxc, l2_Wxo,
        l2_Whi, l2_Whf, l2_Whc, l2_Who,
        Wout);
    proj_kernel<<<BT / 64, 256, 0, stream>>>(x, pre2h);

    if (ws_size >= pre_bytes + h2_bytes) {
        float* h2buf = (float*)((char*)d_ws + pre_bytes);
        lstm_scan_kernel<true><<<BATCH, 128, 0, stream>>>(
            pre2h, l2_bi, l2_bf, l2_bc, l2_bo, bout, h2buf, out);
        head_kernel<<<BT / 256, 256, 0, stream>>>(h2buf, Wout, bout, out);
    } else {
        lstm_scan_kernel<false><<<BATCH, 128, 0, stream>>>(
            pre2h, l2_bi, l2_bf, l2_bc, l2_bo, bout, nullptr, out);
    }
}